// Round 21
// baseline (115.148 us; speedup 1.0000x reference)
//
#include <hip/hip_runtime.h>
#include <hip/hip_bf16.h>

#define S_LEN 2048
#define DIMSZ 1024
#define NH    16
#define HD    64

typedef __attribute__((ext_vector_type(8))) short short8v;
typedef __attribute__((ext_vector_type(4))) short short4v;
typedef __attribute__((ext_vector_type(4))) float f32x4;

typedef const __attribute__((address_space(1))) unsigned GU;
typedef __attribute__((address_space(3))) unsigned LU;

__device__ __forceinline__ void gl16(const ushort* g, ushort* l) {
  __builtin_amdgcn_global_load_lds((GU*)g, (LU*)l, 16, 0, 0);
}

__device__ __forceinline__ ushort f2bf(float f) {
  union { float f; unsigned u; } v; v.f = f;
  unsigned u = v.u;
  return (ushort)((u + 0x7FFFu + ((u >> 16) & 1u)) >> 16);
}

__device__ __forceinline__ uint cvtpk(float lo, float hi) {
  uint d;
  asm("v_cvt_pk_bf16_f32 %0, %1, %2" : "=v"(d) : "v"(lo), "v"(hi));
  return d;
}

// single-instruction 2^x (library exp2f adds range-check insts; scores are
// always <= 0 here and HW underflow to 0 is exactly what we want)
__device__ __forceinline__ float fexp2(float x) {
  float r;
  asm("v_exp_f32 %0, %1" : "=v"(r) : "v"(x));
  return r;
}

__device__ __forceinline__ float fmax3(float a, float b, float c) {
  float r;
  asm("v_max3_f32 %0, %1, %2, %3" : "=v"(r) : "v"(a), "v"(b), "v"(c));
  return r;
}

// ---------------- fp32 -> bf16 pre-convert (x, Wq|Wk|Wv, Wo) --------------
__global__ __launch_bounds__(256) void cvt_k(
    const float* __restrict__ x, const float* __restrict__ wq,
    const float* __restrict__ wk, const float* __restrict__ wv,
    const float* __restrict__ wo,
    ushort* __restrict__ xb, ushort* __restrict__ wqkvb, ushort* __restrict__ wob)
{
  size_t gid = (size_t)blockIdx.x * 256 + threadIdx.x;
  size_t e0 = gid * 8;
  const float* src; ushort* dst;
  if (e0 < (4u << 20)) { src = x + e0; dst = xb + e0; }
  else if (e0 < (7u << 20)) {
    size_t o = e0 - (4u << 20);
    const float* w = (o < (1u << 20)) ? wq : ((o < (2u << 20)) ? wk : wv);
    src = w + (o & ((1u << 20) - 1)); dst = wqkvb + o;
  } else {
    size_t o = e0 - (7u << 20);
    src = wo + o; dst = wob + o;
  }
  float4 a = *(const float4*)src;
  float4 b = *(const float4*)(src + 4);
  short8v h;
  h[0] = (short)f2bf(a.x); h[1] = (short)f2bf(a.y);
  h[2] = (short)f2bf(a.z); h[3] = (short)f2bf(a.w);
  h[4] = (short)f2bf(b.x); h[5] = (short)f2bf(b.y);
  h[6] = (short)f2bf(b.z); h[7] = (short)f2bf(b.w);
  *(short8v*)dst = h;
}

// -------- RoPE cos/sin table, [f][s] layout: tab[f*2048+s] = {cos,sin} ----
__global__ __launch_bounds__(256) void rope_table_k(float2* __restrict__ tab) {
  int i = blockIdx.x * 256 + threadIdx.x;      // < 32*2048
  int f = i >> 11, s = i & (S_LEN - 1);
  float inv = powf(10000.f, -(float)f * (1.f / 32.f));
  float ang = (float)s * inv;
  tab[i] = make_float2(cosf(ang), sinf(ang));
}

// ---------------- QKV projection + RoPE, bf16 MFMA GEMM -------------------
// BK=32, TRI-buffered (48KB LDS); SINGLE barrier per round:
// stage(kt+2) -> compute(kt) -> counted vmcnt -> barrier.
#define QSTAGE(c_, kt_) do {                                                    \
    int k0_ = (kt_) * 32 + colo;                                                \
    gl16(xb + (size_t)(bm + rj0     ) * DIMSZ + k0_, shm + (c_)*4096 + w*1024);       \
    gl16(xb + (size_t)(bm + rj0 + 16) * DIMSZ + k0_, shm + (c_)*4096 + w*1024 + 512); \
    gl16(Wp + (size_t)(bn + rj0     ) * DIMSZ + k0_, shm + 12288 + (c_)*4096 + w*1024);       \
    gl16(Wp + (size_t)(bn + rj0 + 16) * DIMSZ + k0_, shm + 12288 + (c_)*4096 + w*1024 + 512); \
  } while (0)

__global__ __launch_bounds__(256, 4) void gemm_qkv_k(
    const ushort* __restrict__ xb, const ushort* __restrict__ wqkvb,
    ushort* __restrict__ qb, ushort* __restrict__ kb, ushort* __restrict__ vtb,
    const float2* __restrict__ rtab)
{
  __shared__ ushort shm[6 * 4096];   // [0,12288): A tri-buf; [12288,24576): B
  const int t = threadIdx.x;
  int id = blockIdx.x;
  int nid = (id & 7) * 96 + (id >> 3);
  const int which = nid >> 8;
  const int bm = ((nid >> 3) & 31) * 128, bn = (nid & 7) * 128;
  const ushort* Wp = wqkvb + ((size_t)which << 20);
  const int w = t >> 6, l = t & 63, lr = l & 15, lg = l >> 4;
  const int wm = (w >> 1) * 64, wn = (w & 1) * 64;

  const int sub  = (l & 7) ^ (l >> 3);
  const int rj0  = 2 * (w * 16 + (l >> 3)) + (sub >> 2);
  const int colo = (sub & 3) * 8;

  const int lane_off = (lr >> 1) * 128 + (((((lr & 1) << 2) | lg) ^ (lr >> 1)) << 4);
  const int wm2 = wm >> 1, wn2 = wn >> 1;

  f32x4 acc[4][4] = {};

  QSTAGE(0, 0);
  QSTAGE(1, 1);
  asm volatile("s_waitcnt vmcnt(4)" ::: "memory");   // tile0 landed
  __builtin_amdgcn_s_barrier();
  asm volatile("" ::: "memory");

  int c0 = 0, c1 = 1, c2 = 2;
  for (int kt = 0; kt < 32; ++kt) {
    if (kt + 2 < 32) QSTAGE(c2, kt + 2);   // overwrites tile kt-1's buffer (safe)
    const char* lAc = (const char*)(shm + c0 * 4096);
    const char* lBc = (const char*)(shm + 12288 + c0 * 4096);
    short8v a[4], b[4];
    #pragma unroll
    for (int mt = 0; mt < 4; ++mt)
      a[mt] = *(const short8v*)(lAc + (wm2 + mt * 8) * 128 + lane_off);
    #pragma unroll
    for (int nt = 0; nt < 4; ++nt)
      b[nt] = *(const short8v*)(lBc + (wn2 + nt * 8) * 128 + lane_off);
    #pragma unroll
    for (int mt = 0; mt < 4; ++mt)
      #pragma unroll
      for (int nt = 0; nt < 4; ++nt)
        acc[mt][nt] = __builtin_amdgcn_mfma_f32_16x16x32_bf16(b[nt], a[mt], acc[mt][nt], 0, 0, 0);
    if (kt + 2 < 32) {
      asm volatile("s_waitcnt vmcnt(4)" ::: "memory");   // tile kt+1 landed
    } else {
      asm volatile("s_waitcnt vmcnt(0)" ::: "memory");
    }
    __builtin_amdgcn_s_barrier();
    asm volatile("" ::: "memory");
    int tmp = c0; c0 = c1; c1 = c2; c2 = tmp;
  }

  const int bb = bm >> 11, s_base = bm & (S_LEN - 1);

  if (which == 2) {
    // V: transpose via LDS bounce -> coalesced [bh][d][k'] stores (sigma
    // layout: within each 64-k block, k=(kk<<5)|(a'<<4)|(lg<<2)|c stored at
    // col' = (kk<<5)|(lg<<3)|(a'<<2)|c for flash's in-lane P)
    ushort* tb = shm;
    __syncthreads();
    #pragma unroll
    for (int mt = 0; mt < 4; ++mt)
      #pragma unroll
      for (int nt = 0; nt < 4; ++nt)
        #pragma unroll
        for (int r = 0; r < 4; ++r) {
          int row = wn + nt * 16 + lg * 4 + r;     // d-side 0..127
          int col = wm + mt * 16 + lr;             // s-side 0..127
          int byte = row * 256 + ((col * 2) ^ (((row >> 2) & 3) << 5));
          *(ushort*)((char*)tb + byte) = f2bf(acc[mt][nt][r]);
        }
    __syncthreads();
    int row = t >> 1, half = t & 1;
    int h = (bn + row) >> 6, d = (bn + row) & 63;
    int swz = ((row >> 2) & 3) << 5;
    ushort* vdst = vtb + ((size_t)(bb * NH + h) * HD + d) * S_LEN + s_base + half * 64;
    #pragma unroll
    for (int j = 0; j < 8; ++j) {
      int kk = j >> 2, lgi = j & 3;
      int b0 = row * 256 + ((half * 128 + kk * 64 + lgi * 8) ^ swz);
      int b1 = row * 256 + ((half * 128 + kk * 64 + 32 + lgi * 8) ^ swz);
      uint2 lo = *(const uint2*)((const char*)tb + b0);
      uint2 hi = *(const uint2*)((const char*)tb + b1);
      uint4 st; st.x = lo.x; st.y = lo.y; st.z = hi.x; st.w = hi.y;
      *(uint4*)(vdst + j * 8) = st;
    }
  } else {
    // Q/K: in-lane RoPE; Q additionally pre-scaled by 0.125*log2(e)
    ushort* dst = (which == 0) ? qb : kb;
    const float QS = (which == 0) ? (0.125f * 1.4426950408889634f) : 1.0f;
    #pragma unroll
    for (int mt = 0; mt < 4; ++mt) {
      int s = s_base + wm + mt * 16 + lr;
      #pragma unroll
      for (int nt = 0; nt < 4; ++nt) {
        int nw = bn + wn + nt * 16 + lg * 4;
        int h = nw >> 6, d0 = nw & 63;
        uint pk[2];
        #pragma unroll
        for (int rp = 0; rp < 2; ++rp) {
          float2 cs = rtab[(d0 >> 1) * S_LEN + rp * S_LEN + s];
          float t1 = acc[mt][nt][2 * rp], t2 = acc[mt][nt][2 * rp + 1];
          float o0 = (t1 * cs.x - t2 * cs.y) * QS;
          float o1 = (t1 * cs.y + t2 * cs.x) * QS;
          pk[rp] = (uint)f2bf(o0) | ((uint)f2bf(o1) << 16);
        }
        uint2 pv; pv.x = pk[0]; pv.y = pk[1];
        *(uint2*)(dst + ((size_t)(bb * NH + h) * S_LEN + s) * HD + d0) = pv;
      }
    }
  }
}

// ---------------- Flash attention (causal), paired q-tiles ----------------
// Each block owns qtA = 31-u (long) and qtB = u (short); both consume the
// same staged K/V stream (tiles 0..u serve BOTH computations). Same 4 waves
// compute both tiles serially per round -> no cross-merge needed.
// scores in log2 units (Q pre-scaled); defer-max THR=8; in-lane P (sigma vtb)
template<bool DIAG>
__device__ __forceinline__ void attn_tile(
    const ushort* lK, const ushort* lV,
    const short8v* qf, f32x4* o, float& m2, float& lsum,
    int lr, int lg, int wrow)
{
  f32x4 sacc[4] = {};
  __builtin_amdgcn_s_setprio(1);
  #pragma unroll
  for (int kk = 0; kk < 2; ++kk)
    #pragma unroll
    for (int jt = 0; jt < 4; ++jt) {
      int row = jt * 16 + lr;
      short8v kf = *(const short8v*)((const char*)lK + row * 128 + ((kk * 64 + lg * 16) ^ ((row & 7) << 4)));
      sacc[jt] = __builtin_amdgcn_mfma_f32_16x16x32_bf16(kf, qf[kk], sacc[jt], 0, 0, 0);
    }
  __builtin_amdgcn_s_setprio(0);

  float v2[4][4];
  #pragma unroll
  for (int jt = 0; jt < 4; ++jt)
    #pragma unroll
    for (int r = 0; r < 4; ++r) {
      float sv = sacc[jt][r];
      if (DIAG && (jt * 16 + lg * 4 + r > wrow + lr)) sv = -3e38f;
      v2[jt][r] = sv;
    }
  float mj[4];
  #pragma unroll
  for (int jt = 0; jt < 4; ++jt)
    mj[jt] = fmaxf(fmax3(v2[jt][0], v2[jt][1], v2[jt][2]), v2[jt][3]);
  float pmax = fmaxf(fmax3(mj[0], mj[1], mj[2]), mj[3]);

  const bool need = __any(pmax > m2 + 8.f);
  float mn = m2;
  float so = 1.f;
  if (need) {
    float rmax = pmax;
    rmax = fmaxf(rmax, __shfl_xor(rmax, 16));
    rmax = fmaxf(rmax, __shfl_xor(rmax, 32));
    mn = fmaxf(m2, rmax);
    so = fexp2(m2 - mn);
    m2 = mn;
  }
  float pe[4][4];
  float ps = 0.f;
  #pragma unroll
  for (int jt = 0; jt < 4; ++jt)
    #pragma unroll
    for (int r = 0; r < 4; ++r) {
      pe[jt][r] = fexp2(v2[jt][r] - mn);
      ps += pe[jt][r];
    }
  if (need) {
    lsum = lsum * so + ps;
    #pragma unroll
    for (int r = 0; r < 4; ++r) {
      float sor = __shfl(so, lg * 4 + r);
      #pragma unroll
      for (int dt = 0; dt < 4; ++dt) o[dt][r] *= sor;
    }
  } else {
    lsum += ps;
  }

  // PV with in-lane A-fragments; single b128 V reads (sigma-permuted vtb)
  __builtin_amdgcn_s_setprio(1);
  #pragma unroll
  for (int kk = 0; kk < 2; ++kk) {
    union { short8v v; uint u[4]; } pu;
    pu.u[0] = cvtpk(pe[2 * kk][0], pe[2 * kk][1]);
    pu.u[1] = cvtpk(pe[2 * kk][2], pe[2 * kk][3]);
    pu.u[2] = cvtpk(pe[2 * kk + 1][0], pe[2 * kk + 1][1]);
    pu.u[3] = cvtpk(pe[2 * kk + 1][2], pe[2 * kk + 1][3]);
    #pragma unroll
    for (int dt = 0; dt < 4; ++dt) {
      int row = dt * 16 + lr;
      short8v vb = *(const short8v*)((const char*)lV + row * 128 + ((kk * 64 + lg * 16) ^ ((row & 7) << 4)));
      o[dt] = __builtin_amdgcn_mfma_f32_16x16x32_bf16(pu.v, vb, o[dt], 0, 0, 0);
    }
  }
  __builtin_amdgcn_s_setprio(0);
}

__device__ __forceinline__ void store_tile(
    ushort* __restrict__ ab, int bh, int qt, int w, int lr, int lg,
    const f32x4* o, float lsum)
{
  float lf = lsum;
  lf += __shfl_xor(lf, 16);
  lf += __shfl_xor(lf, 32);
  int b = bh >> 4, h = bh & 15;
  #pragma unroll
  for (int r = 0; r < 4; ++r) {
    float li = __shfl(lf, lg * 4 + r);
    float inv = 1.f / li;
    int qg = qt * 64 + w * 16 + lg * 4 + r;
    #pragma unroll
    for (int dt = 0; dt < 4; ++dt)
      ab[((size_t)b * S_LEN + qg) * DIMSZ + h * HD + dt * 16 + lr] = f2bf(o[dt][r] * inv);
  }
}

#define STAGE(c, ktile) do {                                                  \
    int kk0_ = (ktile) * 64;                                                  \
    _Pragma("unroll")                                                         \
    for (int j_ = 0; j_ < 2; ++j_) {                                          \
      int R_ = w * 16 + j_ * 8;                                               \
      gl16(kbh + (size_t)(kk0_ + R_ + r8) * HD + cswz, &lKb[c][R_ * 64]);     \
      gl16(vbh + (size_t)(R_ + r8) * S_LEN + kk0_ + cswz, &lVb[c][R_ * 64]);  \
    }                                                                         \
  } while (0)

__global__ __launch_bounds__(256, 3) void flash_k(
    const ushort* __restrict__ qb, const ushort* __restrict__ kb,
    const ushort* __restrict__ vtb, ushort* __restrict__ ab)
{
  __shared__ ushort lKb[3][64 * 64];   // 24 KB
  __shared__ ushort lVb[3][64 * 64];   // 24 KB -> 48 KB total, 3 blocks/CU

  // 512 blocks, XCD-chunked (64/chunk); within chunk u ascending
  // (longest pairs dispatch first)
  int id = blockIdx.x;
  int nid = (id & 7) * 64 + (id >> 3);
  const int bh = nid >> 4;
  const int u  = nid & 15;
  const int qtA = 31 - u, qtB = u;     // qtB <= 15 < 16 <= qtA
  const int NT = qtA + 1;

  const int t = threadIdx.x, w = t >> 6, l = t & 63, lr = l & 15, lg = l >> 4;
  const int r8 = l >> 3;
  const int cswz = ((l & 7) ^ r8) * 8;
  const ushort* kbh = kb + (size_t)bh * S_LEN * HD;
  const ushort* vbh = vtb + (size_t)bh * HD * S_LEN;

  short8v qfA[2], qfB[2];
  #pragma unroll
  for (int kk = 0; kk < 2; ++kk) {
    qfA[kk] = *(const short8v*)(qb + ((size_t)bh * S_LEN + qtA * 64 + w * 16 + lr) * HD + kk * 32 + lg * 8);
    qfB[kk] = *(const short8v*)(qb + ((size_t)bh * S_LEN + qtB * 64 + w * 16 + lr) * HD + kk * 32 + lg * 8);
  }

  float mA = -3e38f, lsA = 0.f, mB = -3e38f, lsB = 0.f;
  f32x4 oA[4] = {}, oB[4] = {};

  // tri-buffered, counted-vmcnt pipeline (stage kt+2 while kt computes)
  STAGE(0, 0);
  STAGE(1, 1);
  asm volatile("s_waitcnt vmcnt(4)" ::: "memory");   // qf + tile0 landed
  __builtin_amdgcn_s_barrier();
  asm volatile("" ::: "memory");

  int c0 = 0, c1 = 1, c2 = 2;
  for (int kt = 0; kt < NT; ++kt) {
    if (kt + 2 < NT) STAGE(c2, kt + 2);
    const ushort* lK = lKb[c0];
    const ushort* lV = lVb[c0];
    // long tile A (every round)
    if (kt == qtA) attn_tile<true >(lK, lV, qfA, oA, mA, lsA, lr, lg, w * 16);
    else           attn_tile<false>(lK, lV, qfA, oA, mA, lsA, lr, lg, w * 16);
    // short tile B (rounds 0..qtB only)
    if (kt <= qtB) {
      if (kt == qtB) attn_tile<true >(lK, lV, qfB, oB, mB, lsB, lr, lg, w * 16);
      else           attn_tile<false>(lK, lV, qfB, oB, mB, lsB, lr, lg, w * 16);
    }
    if (kt + 1 < NT) {
      asm volatile("s_waitcnt vmcnt(4)" ::: "memory");   // tile kt+1 landed
    } else {
      asm volatile("s_waitcnt vmcnt(0)" ::: "memory");
    }
    __builtin_amdgcn_s_barrier();
    asm volatile("" ::: "memory");
    int tmp = c0; c0 = c1; c1 = c2; c2 = tmp;
  }

  store_tile(ab, bh, qtA, w, lr, lg, oA, lsA);
  store_tile(ab, bh, qtB, w, lr, lg, oB, lsB);
}

// -------- Output projection: out = ab @ Wo^T (fp32 out), 64x128 tiles -----
#define OSTAGE(c, kt_) do {                                                     \
    int k0_ = (kt_) * 64;                                                       \
    _Pragma("unroll")                                                           \
    for (int j_ = 0; j_ < 2; ++j_) {                                            \
      int R_ = w * 16 + j_ * 8;                                                 \
      gl16(ab + (size_t)(bm + R_ + r8) * DIMSZ + k0_ + cswz, &lA[c][R_ * 64]);  \
    }                                                                           \
    _Pragma("unroll")                                                           \
    for (int j_ = 0; j_ < 4; ++j_) {                                            \
      int R_ = w * 32 + j_ * 8;                                                 \
      gl16(wob + (size_t)(bn + R_ + r8) * DIMSZ + k0_ + cswz, &lB[c][R_ * 64]); \
    }                                                                           \
  } while (0)

__global__ __launch_bounds__(256, 4) void gemm_out_k(
    const ushort* __restrict__ ab, const ushort* __restrict__ wob, float* __restrict__ out)
{
  __shared__ ushort lA[2][64 * 64];
  __shared__ ushort lB[2][128 * 64];
  const int t = threadIdx.x;
  int id = blockIdx.x;
  int nid = (id & 7) * 64 + (id >> 3);
  const int bm = (nid >> 3) * 64, bn = (nid & 7) * 128;
  const int w = t >> 6, l = t & 63, lr = l & 15, lg = l >> 4;
  const int wm = (w >> 1) * 32, wn = (w & 1) * 64;
  const int r8 = l >> 3;
  const int cswz = ((l & 7) ^ r8) * 8;

  f32x4 acc[2][4] = {};

  OSTAGE(0, 0);
  for (int kt = 0; kt < DIMSZ / 64; ++kt) {
    const int cur = kt & 1;
    if (kt + 1 < DIMSZ / 64) {
      OSTAGE(cur ^ 1, kt + 1);
      asm volatile("s_waitcnt vmcnt(6)" ::: "memory");
    } else {
      asm volatile("s_waitcnt vmcnt(0)" ::: "memory");
    }
    __builtin_amdgcn_s_barrier();
    asm volatile("" ::: "memory");
    #pragma unroll
    for (int kk = 0; kk < 2; ++kk) {
      short8v a[2], b[4];
      #pragma unroll
      for (int mt = 0; mt < 2; ++mt) {
        int row = wm + mt * 16 + lr;
        a[mt] = *(const short8v*)((const char*)lA[cur] + row * 128 + ((kk * 64 + lg * 16) ^ ((row & 7) << 4)));
      }
      #pragma unroll
      for (int nt = 0; nt < 4; ++nt) {
        int row = wn + nt * 16 + lr;
        b[nt] = *(const short8v*)((const char*)lB[cur] + row * 128 + ((kk * 64 + lg * 16) ^ ((row & 7) << 4)));
      }
      #pragma unroll
      for (int mt = 0; mt < 2; ++mt)
        #pragma unroll
        for (int nt = 0; nt < 4; ++nt)
          acc[mt][nt] = __builtin_amdgcn_mfma_f32_16x16x32_bf16(b[nt], a[mt], acc[mt][nt], 0, 0, 0);
    }
    __builtin_amdgcn_s_barrier();
    asm volatile("" ::: "memory");
  }

  #pragma unroll
  for (int mt = 0; mt < 2; ++mt) {
    int m = bm + wm + mt * 16 + lr;
    #pragma unroll
    for (int nt = 0; nt < 4; ++nt) {
      int nb = bn + wn + nt * 16 + lg * 4;
      *(f32x4*)(out + (size_t)m * DIMSZ + nb) = acc[mt][nt];
    }
  }
}

extern "C" void kernel_launch(void* const* d_in, const int* in_sizes, int n_in,
                              void* d_out, int out_size, void* d_ws, size_t ws_size,
                              hipStream_t stream) {
  (void)in_sizes; (void)n_in; (void)out_size; (void)ws_size;
  const float* x  = (const float*)d_in[0];
  const float* Wq = (const float*)d_in[1];
  const float* Wk = (const float*)d_in[2];
  const float* Wv = (const float*)d_in[3];
  const float* Wo = (const float*)d_in[4];
  float* out = (float*)d_out;

  char* ws = (char*)d_ws;
  ushort* qb    = (ushort*)(ws);                       // 8 MB
  ushort* kb    = (ushort*)(ws + ((size_t)8  << 20));  // 8 MB
  ushort* vtb   = (ushort*)(ws + ((size_t)16 << 20));  // 8 MB
  ushort* xb    = (ushort*)(ws + ((size_t)24 << 20));  // 8 MB (xb, reused as ab)
  ushort* ab    = xb;                                  // lifetime disjoint
  ushort* wqkvb = (ushort*)(ws + ((size_t)32 << 20));  // 6 MB
  ushort* wob   = (ushort*)(ws + ((size_t)38 << 20));  // 2 MB
  float2* rtab  = (float2*)(ws + ((size_t)40 << 20));  // 512 KB

  hipLaunchKernelGGL(cvt_k, dim3(4096), dim3(256), 0, stream,
                     x, Wq, Wk, Wv, Wo, xb, wqkvb, wob);
  hipLaunchKernelGGL(rope_table_k, dim3(S_LEN * 32 / 256), dim3(256), 0, stream, rtab);
  hipLaunchKernelGGL(gemm_qkv_k, dim3(768), dim3(256), 0, stream,
                     xb, wqkvb, qb, kb, vtb, rtab);
  hipLaunchKernelGGL(flash_k, dim3(512), dim3(256), 0, stream, qb, kb, vtb, ab);
  hipLaunchKernelGGL(gemm_out_k, dim3(512), dim3(256), 0, stream, ab, wob, out);
}

// Round 22
// 111.116 us; speedup vs baseline: 1.0363x; 1.0363x over previous
//
#include <hip/hip_runtime.h>
#include <hip/hip_bf16.h>

#define S_LEN 2048
#define DIMSZ 1024
#define NH    16
#define HD    64

typedef __attribute__((ext_vector_type(8))) short short8v;
typedef __attribute__((ext_vector_type(4))) short short4v;
typedef __attribute__((ext_vector_type(4))) float f32x4;

typedef const __attribute__((address_space(1))) unsigned GU;
typedef __attribute__((address_space(3))) unsigned LU;

__device__ __forceinline__ void gl16(const ushort* g, ushort* l) {
  __builtin_amdgcn_global_load_lds((GU*)g, (LU*)l, 16, 0, 0);
}

__device__ __forceinline__ ushort f2bf(float f) {
  union { float f; unsigned u; } v; v.f = f;
  unsigned u = v.u;
  return (ushort)((u + 0x7FFFu + ((u >> 16) & 1u)) >> 16);
}

__device__ __forceinline__ uint cvtpk(float lo, float hi) {
  uint d;
  asm("v_cvt_pk_bf16_f32 %0, %1, %2" : "=v"(d) : "v"(lo), "v"(hi));
  return d;
}

// single-instruction 2^x (library exp2f adds range-check insts; scores are
// always <= 0 here and HW underflow to 0 is exactly what we want)
__device__ __forceinline__ float fexp2(float x) {
  float r;
  asm("v_exp_f32 %0, %1" : "=v"(r) : "v"(x));
  return r;
}

__device__ __forceinline__ float fmax3(float a, float b, float c) {
  float r;
  asm("v_max3_f32 %0, %1, %2, %3" : "=v"(r) : "v"(a), "v"(b), "v"(c));
  return r;
}

// ------- fp32 -> bf16 pre-convert (x, Wq|Wk|Wv, Wo) + RoPE table ----------
// blocks [0,4096): convert 8M elements; blocks [4096,4352): rope table
__global__ __launch_bounds__(256) void cvt_k(
    const float* __restrict__ x, const float* __restrict__ wq,
    const float* __restrict__ wk, const float* __restrict__ wv,
    const float* __restrict__ wo,
    ushort* __restrict__ xb, ushort* __restrict__ wqkvb, ushort* __restrict__ wob,
    float2* __restrict__ rtab)
{
  if (blockIdx.x >= 4096) {
    int i = (blockIdx.x - 4096) * 256 + threadIdx.x;   // < 32*2048
    int f = i >> 11, s = i & (S_LEN - 1);
    float inv = powf(10000.f, -(float)f * (1.f / 32.f));
    float ang = (float)s * inv;
    rtab[i] = make_float2(cosf(ang), sinf(ang));
    return;
  }
  size_t gid = (size_t)blockIdx.x * 256 + threadIdx.x;
  size_t e0 = gid * 8;
  const float* src; ushort* dst;
  if (e0 < (4u << 20)) { src = x + e0; dst = xb + e0; }
  else if (e0 < (7u << 20)) {
    size_t o = e0 - (4u << 20);
    const float* w = (o < (1u << 20)) ? wq : ((o < (2u << 20)) ? wk : wv);
    src = w + (o & ((1u << 20) - 1)); dst = wqkvb + o;
  } else {
    size_t o = e0 - (7u << 20);
    src = wo + o; dst = wob + o;
  }
  float4 a = *(const float4*)src;
  float4 b = *(const float4*)(src + 4);
  short8v h;
  h[0] = (short)f2bf(a.x); h[1] = (short)f2bf(a.y);
  h[2] = (short)f2bf(a.z); h[3] = (short)f2bf(a.w);
  h[4] = (short)f2bf(b.x); h[5] = (short)f2bf(b.y);
  h[6] = (short)f2bf(b.z); h[7] = (short)f2bf(b.w);
  *(short8v*)dst = h;
}

// ---------------- QKV projection + RoPE, bf16 MFMA GEMM -------------------
// BK=32, TRI-buffered (48KB LDS); counted vmcnt, 2-deep prefetch.
#define QSTAGE(c_, kt_) do {                                                    \
    int k0_ = (kt_) * 32 + colo;                                                \
    gl16(xb + (size_t)(bm + rj0     ) * DIMSZ + k0_, shm + (c_)*4096 + w*1024);       \
    gl16(xb + (size_t)(bm + rj0 + 16) * DIMSZ + k0_, shm + (c_)*4096 + w*1024 + 512); \
    gl16(Wp + (size_t)(bn + rj0     ) * DIMSZ + k0_, shm + 12288 + (c_)*4096 + w*1024);       \
    gl16(Wp + (size_t)(bn + rj0 + 16) * DIMSZ + k0_, shm + 12288 + (c_)*4096 + w*1024 + 512); \
  } while (0)

__global__ __launch_bounds__(256, 4) void gemm_qkv_k(
    const ushort* __restrict__ xb, const ushort* __restrict__ wqkvb,
    ushort* __restrict__ qb, ushort* __restrict__ kb, ushort* __restrict__ vtb,
    const float2* __restrict__ rtab)
{
  __shared__ ushort shm[6 * 4096];   // [0,12288): A tri-buf; [12288,24576): B
  const int t = threadIdx.x;
  int id = blockIdx.x;
  int nid = (id & 7) * 96 + (id >> 3);
  const int which = nid >> 8;
  const int bm = ((nid >> 3) & 31) * 128, bn = (nid & 7) * 128;
  const ushort* Wp = wqkvb + ((size_t)which << 20);
  const int w = t >> 6, l = t & 63, lr = l & 15, lg = l >> 4;
  const int wm = (w >> 1) * 64, wn = (w & 1) * 64;

  const int sub  = (l & 7) ^ (l >> 3);
  const int rj0  = 2 * (w * 16 + (l >> 3)) + (sub >> 2);
  const int colo = (sub & 3) * 8;

  const int lane_off = (lr >> 1) * 128 + (((((lr & 1) << 2) | lg) ^ (lr >> 1)) << 4);
  const int wm2 = wm >> 1, wn2 = wn >> 1;

  f32x4 acc[4][4] = {};

  QSTAGE(0, 0);
  QSTAGE(1, 1);
  int c0 = 0, c1 = 1, c2 = 2;
  for (int kt = 0; kt < 32; ++kt) {
    if (kt + 2 < 32) {
      QSTAGE(c2, kt + 2);
      asm volatile("s_waitcnt vmcnt(8)" ::: "memory");
    } else if (kt + 1 < 32) {
      asm volatile("s_waitcnt vmcnt(4)" ::: "memory");
    } else {
      asm volatile("s_waitcnt vmcnt(0)" ::: "memory");
    }
    __builtin_amdgcn_s_barrier();
    asm volatile("" ::: "memory");
    const char* lAc = (const char*)(shm + c0 * 4096);
    const char* lBc = (const char*)(shm + 12288 + c0 * 4096);
    short8v a[4], b[4];
    #pragma unroll
    for (int mt = 0; mt < 4; ++mt)
      a[mt] = *(const short8v*)(lAc + (wm2 + mt * 8) * 128 + lane_off);
    #pragma unroll
    for (int nt = 0; nt < 4; ++nt)
      b[nt] = *(const short8v*)(lBc + (wn2 + nt * 8) * 128 + lane_off);
    #pragma unroll
    for (int mt = 0; mt < 4; ++mt)
      #pragma unroll
      for (int nt = 0; nt < 4; ++nt)
        acc[mt][nt] = __builtin_amdgcn_mfma_f32_16x16x32_bf16(b[nt], a[mt], acc[mt][nt], 0, 0, 0);
    __builtin_amdgcn_s_barrier();
    asm volatile("" ::: "memory");
    int tmp = c0; c0 = c1; c1 = c2; c2 = tmp;
  }

  const int bb = bm >> 11, s_base = bm & (S_LEN - 1);

  if (which == 2) {
    // V: transpose via LDS bounce -> coalesced [bh][d][k'] stores (sigma
    // layout: within each 64-k block, k=(kk<<5)|(a'<<4)|(lg<<2)|c stored at
    // col' = (kk<<5)|(lg<<3)|(a'<<2)|c for flash's in-lane P)
    ushort* tb = shm;
    __syncthreads();
    #pragma unroll
    for (int mt = 0; mt < 4; ++mt)
      #pragma unroll
      for (int nt = 0; nt < 4; ++nt)
        #pragma unroll
        for (int r = 0; r < 4; ++r) {
          int row = wn + nt * 16 + lg * 4 + r;     // d-side 0..127
          int col = wm + mt * 16 + lr;             // s-side 0..127
          int byte = row * 256 + ((col * 2) ^ (((row >> 2) & 3) << 5));
          *(ushort*)((char*)tb + byte) = f2bf(acc[mt][nt][r]);
        }
    __syncthreads();
    int row = t >> 1, half = t & 1;
    int h = (bn + row) >> 6, d = (bn + row) & 63;
    int swz = ((row >> 2) & 3) << 5;
    ushort* vdst = vtb + ((size_t)(bb * NH + h) * HD + d) * S_LEN + s_base + half * 64;
    #pragma unroll
    for (int j = 0; j < 8; ++j) {
      int kk = j >> 2, lgi = j & 3;
      int b0 = row * 256 + ((half * 128 + kk * 64 + lgi * 8) ^ swz);
      int b1 = row * 256 + ((half * 128 + kk * 64 + 32 + lgi * 8) ^ swz);
      uint2 lo = *(const uint2*)((const char*)tb + b0);
      uint2 hi = *(const uint2*)((const char*)tb + b1);
      uint4 st; st.x = lo.x; st.y = lo.y; st.z = hi.x; st.w = hi.y;
      *(uint4*)(vdst + j * 8) = st;
    }
  } else {
    // Q/K: in-lane RoPE; Q additionally pre-scaled by 0.125*log2(e)
    ushort* dst = (which == 0) ? qb : kb;
    const float QS = (which == 0) ? (0.125f * 1.4426950408889634f) : 1.0f;
    #pragma unroll
    for (int mt = 0; mt < 4; ++mt) {
      int s = s_base + wm + mt * 16 + lr;
      #pragma unroll
      for (int nt = 0; nt < 4; ++nt) {
        int nw = bn + wn + nt * 16 + lg * 4;
        int h = nw >> 6, d0 = nw & 63;
        uint pk[2];
        #pragma unroll
        for (int rp = 0; rp < 2; ++rp) {
          float2 cs = rtab[(d0 >> 1) * S_LEN + rp * S_LEN + s];
          float t1 = acc[mt][nt][2 * rp], t2 = acc[mt][nt][2 * rp + 1];
          float o0 = (t1 * cs.x - t2 * cs.y) * QS;
          float o1 = (t1 * cs.y + t2 * cs.x) * QS;
          pk[rp] = (uint)f2bf(o0) | ((uint)f2bf(o1) << 16);
        }
        uint2 pv; pv.x = pk[0]; pv.y = pk[1];
        *(uint2*)(dst + ((size_t)(bb * NH + h) * S_LEN + s) * HD + d0) = pv;
      }
    }
  }
}

// ---------------- Flash attention (causal), 4-wave, 1 q-tile/block --------
// scores already in log2 units (Q pre-scaled); defer-max THR=8
// P->PV A-frag fully IN-LANE; vtb is sigma-permuted so the V B-frag is a
// single natural ds_read_b128 per (kk,dt). Bank-conflict-free (measured 0).
template<bool DIAG>
__device__ __forceinline__ void attn_tile(
    const ushort* lK, const ushort* lV,
    const short8v* qf, f32x4* o, float& m2, float& lsum,
    int lr, int lg, int wrow)
{
  f32x4 sacc[4] = {};
  __builtin_amdgcn_s_setprio(1);
  #pragma unroll
  for (int kk = 0; kk < 2; ++kk)
    #pragma unroll
    for (int jt = 0; jt < 4; ++jt) {
      int row = jt * 16 + lr;
      short8v kf = *(const short8v*)((const char*)lK + row * 128 + ((kk * 64 + lg * 16) ^ ((row & 7) << 4)));
      sacc[jt] = __builtin_amdgcn_mfma_f32_16x16x32_bf16(kf, qf[kk], sacc[jt], 0, 0, 0);
    }
  __builtin_amdgcn_s_setprio(0);

  float v2[4][4];
  #pragma unroll
  for (int jt = 0; jt < 4; ++jt)
    #pragma unroll
    for (int r = 0; r < 4; ++r) {
      float sv = sacc[jt][r];
      if (DIAG && (jt * 16 + lg * 4 + r > wrow + lr)) sv = -3e38f;
      v2[jt][r] = sv;
    }
  float mj[4];
  #pragma unroll
  for (int jt = 0; jt < 4; ++jt)
    mj[jt] = fmaxf(fmax3(v2[jt][0], v2[jt][1], v2[jt][2]), v2[jt][3]);
  float pmax = fmaxf(fmax3(mj[0], mj[1], mj[2]), mj[3]);

  const bool need = __any(pmax > m2 + 8.f);
  float mn = m2;
  float so = 1.f;
  if (need) {
    float rmax = pmax;
    rmax = fmaxf(rmax, __shfl_xor(rmax, 16));
    rmax = fmaxf(rmax, __shfl_xor(rmax, 32));
    mn = fmaxf(m2, rmax);
    so = fexp2(m2 - mn);
    m2 = mn;
  }
  float pe[4][4];
  float ps = 0.f;
  #pragma unroll
  for (int jt = 0; jt < 4; ++jt)
    #pragma unroll
    for (int r = 0; r < 4; ++r) {
      pe[jt][r] = fexp2(v2[jt][r] - mn);
      ps += pe[jt][r];
    }
  if (need) {
    lsum = lsum * so + ps;
    #pragma unroll
    for (int r = 0; r < 4; ++r) {
      float sor = __shfl(so, lg * 4 + r);
      #pragma unroll
      for (int dt = 0; dt < 4; ++dt) o[dt][r] *= sor;
    }
  } else {
    lsum += ps;
  }

  // PV with in-lane A-fragments; single b128 V reads (sigma-permuted vtb)
  __builtin_amdgcn_s_setprio(1);
  #pragma unroll
  for (int kk = 0; kk < 2; ++kk) {
    union { short8v v; uint u[4]; } pu;
    pu.u[0] = cvtpk(pe[2 * kk][0], pe[2 * kk][1]);
    pu.u[1] = cvtpk(pe[2 * kk][2], pe[2 * kk][3]);
    pu.u[2] = cvtpk(pe[2 * kk + 1][0], pe[2 * kk + 1][1]);
    pu.u[3] = cvtpk(pe[2 * kk + 1][2], pe[2 * kk + 1][3]);
    #pragma unroll
    for (int dt = 0; dt < 4; ++dt) {
      int row = dt * 16 + lr;
      short8v vb = *(const short8v*)((const char*)lV + row * 128 + ((kk * 64 + lg * 16) ^ ((row & 7) << 4)));
      o[dt] = __builtin_amdgcn_mfma_f32_16x16x32_bf16(pu.v, vb, o[dt], 0, 0, 0);
    }
  }
  __builtin_amdgcn_s_setprio(0);
}

__device__ __forceinline__ void store_tile(
    ushort* __restrict__ ab, int bh, int qt, int w, int lr, int lg,
    const f32x4* o, float lsum)
{
  float lf = lsum;
  lf += __shfl_xor(lf, 16);
  lf += __shfl_xor(lf, 32);
  int b = bh >> 4, h = bh & 15;
  #pragma unroll
  for (int r = 0; r < 4; ++r) {
    float li = __shfl(lf, lg * 4 + r);
    float inv = 1.f / li;
    int qg = qt * 64 + w * 16 + lg * 4 + r;
    #pragma unroll
    for (int dt = 0; dt < 4; ++dt)
      ab[((size_t)b * S_LEN + qg) * DIMSZ + h * HD + dt * 16 + lr] = f2bf(o[dt][r] * inv);
  }
}

#define STAGE(c, ktile) do {                                                  \
    int kk0_ = (ktile) * 64;                                                  \
    _Pragma("unroll")                                                         \
    for (int j_ = 0; j_ < 2; ++j_) {                                          \
      int R_ = w * 16 + j_ * 8;                                               \
      gl16(kbh + (size_t)(kk0_ + R_ + r8) * HD + cswz, &lKb[c][R_ * 64]);     \
      gl16(vbh + (size_t)(R_ + r8) * S_LEN + kk0_ + cswz, &lVb[c][R_ * 64]);  \
    }                                                                         \
  } while (0)

__global__ __launch_bounds__(256, 3) void flash_k(
    const ushort* __restrict__ qb, const ushort* __restrict__ kb,
    const ushort* __restrict__ vtb, ushort* __restrict__ ab)
{
  __shared__ ushort lKb[3][64 * 64];   // 24 KB
  __shared__ ushort lVb[3][64 * 64];   // 24 KB -> 48 KB total, 3 blocks/CU

  int id = blockIdx.x;
  int nid = (id & 7) * 128 + (id >> 3);
  const int bh = (nid >> 7) * 4 + (nid & 3);
  const int qt = 31 - ((nid & 127) >> 2);
  const int NT = qt + 1;

  const int t = threadIdx.x, w = t >> 6, l = t & 63, lr = l & 15, lg = l >> 4;
  const int r8 = l >> 3;
  const int cswz = ((l & 7) ^ r8) * 8;
  const ushort* kbh = kb + (size_t)bh * S_LEN * HD;
  const ushort* vbh = vtb + (size_t)bh * HD * S_LEN;

  short8v qf[2];
  #pragma unroll
  for (int kk = 0; kk < 2; ++kk)
    qf[kk] = *(const short8v*)(qb + ((size_t)bh * S_LEN + qt * 64 + w * 16 + lr) * HD + kk * 32 + lg * 8);

  float m2 = -3e38f, lsum = 0.f;
  f32x4 o[4] = {};

  // tri-buffered, counted-vmcnt pipeline: stage kt+2 while kt computes;
  // round-end waits only for kt+1's 4 loads (kt+2 stays in flight).
  STAGE(0, 0);
  STAGE(1, 1);
  asm volatile("s_waitcnt vmcnt(4)" ::: "memory");
  __builtin_amdgcn_s_barrier();
  asm volatile("" ::: "memory");

  int c0 = 0, c1 = 1, c2 = 2;
  for (int kt = 0; kt < NT; ++kt) {
    if (kt + 2 < NT) STAGE(c2, kt + 2);
    const ushort* lK = lKb[c0];
    const ushort* lV = lVb[c0];
    if (kt == qt) attn_tile<true >(lK, lV, qf, o, m2, lsum, lr, lg, w * 16);
    else          attn_tile<false>(lK, lV, qf, o, m2, lsum, lr, lg, w * 16);
    if (kt + 1 < NT) {
      asm volatile("s_waitcnt vmcnt(4)" ::: "memory");
    } else {
      asm volatile("s_waitcnt vmcnt(0)" ::: "memory");
    }
    __builtin_amdgcn_s_barrier();
    asm volatile("" ::: "memory");
    int tmp = c0; c0 = c1; c1 = c2; c2 = tmp;
  }

  store_tile(ab, bh, qt, w, lr, lg, o, lsum);
}

// -------- Output projection: out = ab @ Wo^T (fp32 out), 64x128 tiles -----
#define OSTAGE(c, kt_) do {                                                     \
    int k0_ = (kt_) * 64;                                                       \
    _Pragma("unroll")                                                           \
    for (int j_ = 0; j_ < 2; ++j_) {                                            \
      int R_ = w * 16 + j_ * 8;                                                 \
      gl16(ab + (size_t)(bm + R_ + r8) * DIMSZ + k0_ + cswz, &lA[c][R_ * 64]);  \
    }                                                                           \
    _Pragma("unroll")                                                           \
    for (int j_ = 0; j_ < 4; ++j_) {                                            \
      int R_ = w * 32 + j_ * 8;                                                 \
      gl16(wob + (size_t)(bn + R_ + r8) * DIMSZ + k0_ + cswz, &lB[c][R_ * 64]); \
    }                                                                           \
  } while (0)

__global__ __launch_bounds__(256, 4) void gemm_out_k(
    const ushort* __restrict__ ab, const ushort* __restrict__ wob, float* __restrict__ out)
{
  __shared__ ushort lA[2][64 * 64];
  __shared__ ushort lB[2][128 * 64];
  const int t = threadIdx.x;
  int id = blockIdx.x;
  int nid = (id & 7) * 64 + (id >> 3);
  const int bm = (nid >> 3) * 64, bn = (nid & 7) * 128;
  const int w = t >> 6, l = t & 63, lr = l & 15, lg = l >> 4;
  const int wm = (w >> 1) * 32, wn = (w & 1) * 64;
  const int r8 = l >> 3;
  const int cswz = ((l & 7) ^ r8) * 8;

  f32x4 acc[2][4] = {};

  OSTAGE(0, 0);
  for (int kt = 0; kt < DIMSZ / 64; ++kt) {
    const int cur = kt & 1;
    if (kt + 1 < DIMSZ / 64) {
      OSTAGE(cur ^ 1, kt + 1);
      asm volatile("s_waitcnt vmcnt(6)" ::: "memory");
    } else {
      asm volatile("s_waitcnt vmcnt(0)" ::: "memory");
    }
    __builtin_amdgcn_s_barrier();
    asm volatile("" ::: "memory");
    #pragma unroll
    for (int kk = 0; kk < 2; ++kk) {
      short8v a[2], b[4];
      #pragma unroll
      for (int mt = 0; mt < 2; ++mt) {
        int row = wm + mt * 16 + lr;
        a[mt] = *(const short8v*)((const char*)lA[cur] + row * 128 + ((kk * 64 + lg * 16) ^ ((row & 7) << 4)));
      }
      #pragma unroll
      for (int nt = 0; nt < 4; ++nt) {
        int row = wn + nt * 16 + lr;
        b[nt] = *(const short8v*)((const char*)lB[cur] + row * 128 + ((kk * 64 + lg * 16) ^ ((row & 7) << 4)));
      }
      #pragma unroll
      for (int mt = 0; mt < 2; ++mt)
        #pragma unroll
        for (int nt = 0; nt < 4; ++nt)
          acc[mt][nt] = __builtin_amdgcn_mfma_f32_16x16x32_bf16(b[nt], a[mt], acc[mt][nt], 0, 0, 0);
    }
    __builtin_amdgcn_s_barrier();
    asm volatile("" ::: "memory");
  }

  #pragma unroll
  for (int mt = 0; mt < 2; ++mt) {
    int m = bm + wm + mt * 16 + lr;
    #pragma unroll
    for (int nt = 0; nt < 4; ++nt) {
      int nb = bn + wn + nt * 16 + lg * 4;
      *(f32x4*)(out + (size_t)m * DIMSZ + nb) = acc[mt][nt];
    }
  }
}

extern "C" void kernel_launch(void* const* d_in, const int* in_sizes, int n_in,
                              void* d_out, int out_size, void* d_ws, size_t ws_size,
                              hipStream_t stream) {
  (void)in_sizes; (void)n_in; (void)out_size; (void)ws_size;
  const float* x  = (const float*)d_in[0];
  const float* Wq = (const float*)d_in[1];
  const float* Wk = (const float*)d_in[2];
  const float* Wv = (const float*)d_in[3];
  const float* Wo = (const float*)d_in[4];
  float* out = (float*)d_out;

  char* ws = (char*)d_ws;
  ushort* qb    = (ushort*)(ws);                       // 8 MB
  ushort* kb    = (ushort*)(ws + ((size_t)8  << 20));  // 8 MB
  ushort* vtb   = (ushort*)(ws + ((size_t)16 << 20));  // 8 MB
  ushort* xb    = (ushort*)(ws + ((size_t)24 << 20));  // 8 MB (xb, reused as ab)
  ushort* ab    = xb;                                  // lifetime disjoint
  ushort* wqkvb = (ushort*)(ws + ((size_t)32 << 20));  // 6 MB
  ushort* wob   = (ushort*)(ws + ((size_t)38 << 20));  // 2 MB
  float2* rtab  = (float2*)(ws + ((size_t)40 << 20));  // 512 KB

  hipLaunchKernelGGL(cvt_k, dim3(4352), dim3(256), 0, stream,
                     x, Wq, Wk, Wv, Wo, xb, wqkvb, wob, rtab);
  hipLaunchKernelGGL(gemm_qkv_k, dim3(768), dim3(256), 0, stream,
                     xb, wqkvb, qb, kb, vtb, rtab);
  hipLaunchKernelGGL(flash_k, dim3(1024), dim3(256), 0, stream, qb, kb, vtb, ab);
  hipLaunchKernelGGL(gemm_out_k, dim3(512), dim3(256), 0, stream, ab, wob, out);
}